// Round 6
// baseline (2560.267 us; speedup 1.0000x reference)
//
#include <hip/hip_runtime.h>
#include <cstdint>
#include <cstddef>

#define EDIM 256
#define HID  512
#define NTAG 12
#define HDIM 256
#define BB   64
#define SS   256
#define START_TAG 10
#define STOP_TAG  11
#define NEGV (-10000.0f)
#define UPW  8           // h-units per WG (32 gate rows)

typedef __attribute__((ext_vector_type(8))) short bf16x8;
typedef __attribute__((ext_vector_type(4))) float f32x4;

__device__ __forceinline__ unsigned short bf16_rne(float x) {
  union { float f; unsigned u; } a; a.f = x;
  return (unsigned short)((a.u + 0x7fffu + ((a.u >> 16) & 1u)) >> 16);
}
__device__ __forceinline__ float bf16_tof(unsigned short h) {
  union { unsigned u; float f; } a; a.u = ((unsigned)h) << 16; return a.f;
}
__device__ __forceinline__ void unpack8(const unsigned* u, bf16x8& hi, bf16x8& lo) {
#pragma unroll
  for (int j = 0; j < 8; ++j) {
    hi[j] = (short)(u[j] & 0xffffu);
    lo[j] = (short)(u[j] >> 16);
  }
}
__device__ __forceinline__ void pack_hilo(const float* xf, bf16x8& hi, bf16x8& lo) {
#pragma unroll
  for (int j = 0; j < 8; ++j) {
    unsigned short hb = bf16_rne(xf[j]);
    hi[j] = (short)hb;
    lo[j] = (short)bf16_rne(xf[j] - bf16_tof(hb));
  }
}

// ---------------- K0: gather + split-bf16 pack  xpk[t][b][k] ---------------
__global__ void k0_gather(const int* __restrict__ sent,
                          const float* __restrict__ emb,
                          unsigned int* __restrict__ xpk) {
  int t = blockIdx.x;
  for (int n = threadIdx.x; n < BB * EDIM; n += 256) {
    int b = n >> 8, k = n & 255;
    int tok = sent[b * SS + t];
    float x = emb[(size_t)tok * EDIM + k];
    unsigned short hb = bf16_rne(x);
    unsigned short lb = bf16_rne(x - bf16_tof(hb));
    xpk[((size_t)t * BB + b) * EDIM + k] = (unsigned)hb | ((unsigned)lb << 16);
  }
}

// ---------------- K1: input projection via split-bf16 MFMA ----------------
__global__ void __launch_bounds__(256)
k1_mfma(const unsigned int* __restrict__ xpk,
        const float* __restrict__ WihF, const float* __restrict__ WihB,
        const float* __restrict__ bihF, const float* __restrict__ bhhF,
        const float* __restrict__ bihB, const float* __restrict__ bhhB,
        float* __restrict__ pre) {
  int blk = blockIdx.x;
  int rg = blk & 15, t = (blk >> 4) & 255, d = blk >> 12;
  const float* Wih = d ? WihB : WihF;
  const float* bi  = d ? bihB : bihF;
  const float* bh2 = d ? bhhB : bhhF;
  int tid = threadIdx.x, lane = tid & 63, v = tid >> 6;
  int l15 = lane & 15, l4 = lane >> 4;

  int Rrow = rg * 64 + v * 16 + l15;
  const float* wrow = Wih + (size_t)Rrow * EDIM;
  bf16x8 Ahi[8], Alo[8];
#pragma unroll
  for (int kk = 0; kk < 8; ++kk) {
    float4 f0 = *(const float4*)(wrow + kk * 32 + l4 * 8);
    float4 f1 = *(const float4*)(wrow + kk * 32 + l4 * 8 + 4);
    float xf[8] = {f0.x, f0.y, f0.z, f0.w, f1.x, f1.y, f1.z, f1.w};
    pack_hilo(xf, Ahi[kk], Alo[kk]);
  }
  float b4[4];
#pragma unroll
  for (int r = 0; r < 4; ++r) {
    int Racc = rg * 64 + v * 16 + l4 * 4 + r;
    b4[r] = bi[Racc] + bh2[Racc];
  }
  const unsigned int* xt = xpk + (size_t)t * BB * EDIM;
  size_t obase = ((size_t)d * SS + t) * 1024 * BB;
#pragma unroll
  for (int ct = 0; ct < 4; ++ct) {
    f32x4 acc = {b4[0], b4[1], b4[2], b4[3]};
    int col = ct * 16 + l15;
    const unsigned int* xc = xt + (size_t)col * EDIM;
#pragma unroll
    for (int kk = 0; kk < 8; ++kk) {
      uint4 q0 = *(const uint4*)(xc + kk * 32 + l4 * 8);
      uint4 q1 = *(const uint4*)(xc + kk * 32 + l4 * 8 + 4);
      unsigned u[8] = {q0.x, q0.y, q0.z, q0.w, q1.x, q1.y, q1.z, q1.w};
      bf16x8 bhf, blf;
      unpack8(u, bhf, blf);
      acc = __builtin_amdgcn_mfma_f32_16x16x32_bf16(Ahi[kk], bhf, acc, 0, 0, 0);
      acc = __builtin_amdgcn_mfma_f32_16x16x32_bf16(Ahi[kk], blf, acc, 0, 0, 0);
      acc = __builtin_amdgcn_mfma_f32_16x16x32_bf16(Alo[kk], bhf, acc, 0, 0, 0);
    }
#pragma unroll
    for (int r = 0; r < 4; ++r) {
      int Racc = rg * 64 + v * 16 + l4 * 4 + r;
      pre[obase + (size_t)Racc * BB + col] = acc[r];
    }
  }
}

// ---------------- K2: persistent BiLSTM, wave-independent shards -----------
// 64 WGs: d = bid>>5, w = bid&31. WG owns h-units [w*8,w*8+8). Wave v owns
// batch cols [v*16,v*16+16) END-TO-END (consume + produce): the 4 waves are
// independent sync shards (batch cols never interact). No LDS, no
// __syncthreads. Gate transpose via one __shfl_xor(·,32); cell state in
// registers. Exchange ring hx[d][slot][col][k] (4 slots); 8B single-writer
// granules (2 units packed); sentinel 0xFF.. poll = the data load itself.
// Producer order: poll -> re-arm slot(s+1) -> compute -> vmcnt(0) -> produce.
__global__ void __launch_bounds__(256, 1)
lstm_mfma(const float* __restrict__ WhhF, const float* __restrict__ WhhB,
          const float* __restrict__ h0, const float* __restrict__ c0,
          const float* __restrict__ pre, float* __restrict__ hseq,
          unsigned long long* __restrict__ hx64) {
  const int bid = blockIdx.x;
  const int d = bid >> 5, w = bid & 31;
  const int tid = threadIdx.x;
  const int lane = tid & 63;
  const int v = tid >> 6;
  const int l15 = lane & 15, l4 = lane >> 4;
  const int bcol = v * 16 + l15;
  const int u2 = ((l4 & 1) << 2) | ((l4 >> 1) << 1);  // lane's unit pair base
  const bool low = (l4 < 2);
  const int kg0 = w * UPW + u2;                        // even global unit
  const float* Whh = d ? WhhB : WhhF;

  // ---- persistent A fragments: A[i][k], i = rt*16+l15, k = kk*32+l4*8+j
  bf16x8 Ahi[2][8], Alo[2][8];
#pragma unroll
  for (int rt = 0; rt < 2; ++rt) {
    int i = rt * 16 + l15;
    int R = ((i >> 3) << 8) + w * UPW + (i & 7);
    const float* wrow = Whh + (size_t)R * HDIM;
#pragma unroll
    for (int kk = 0; kk < 8; ++kk) {
      float4 f0 = *(const float4*)(wrow + kk * 32 + l4 * 8);
      float4 f1 = *(const float4*)(wrow + kk * 32 + l4 * 8 + 4);
      float xf[8] = {f0.x, f0.y, f0.z, f0.w, f1.x, f1.y, f1.z, f1.w};
      pack_hilo(xf, Ahi[rt][kk], Alo[rt][kk]);
    }
  }
  // cell state in registers: units kg0, kg0+1, col bcol
  float c2[2];
  c2[0] = c0[((size_t)d * BB + bcol) * HDIM + kg0];
  c2[1] = c0[((size_t)d * BB + bcol) * HDIM + kg0 + 1];

  for (int s = 0; s < SS; ++s) {
    const int t = d ? (SS - 1 - s) : s;

    // acc init from pre — issued BEFORE the poll to hide HBM latency
    const float* pbase = pre + (((size_t)d * SS + t) * 1024) * BB + bcol;
    f32x4 accA, accD;
#pragma unroll
    for (int r = 0; r < 4; ++r) {
      int i0 = l4 * 4 + r;
      int R0 = ((i0 >> 3) << 8) + w * UPW + (i0 & 7);
      accA[r] = pbase[(size_t)R0 * BB];
      int i1 = 16 + i0;
      int R1 = ((i1 >> 3) << 8) + w * UPW + (i1 & 7);
      accD[r] = pbase[(size_t)R1 * BB];
    }
    f32x4 accB = {0.f, 0.f, 0.f, 0.f}, accC = accB, accE = accB, accF = accB;

    // ---- data-poll: h_{s-1} (this lane's 32 u64 granules) into registers
    unsigned long long uq[32];
    if (s > 0) {
      const unsigned long long* slot =
          hx64 + ((size_t)(d * 4 + ((s - 1) & 3)) * BB + bcol) * 128;
      while (true) {
        int bad = 0;
#pragma unroll
        for (int kk = 0; kk < 8; ++kk)
#pragma unroll
          for (int j2 = 0; j2 < 4; ++j2) {
            unsigned long long val = __hip_atomic_load(
                slot + kk * 16 + l4 * 4 + j2,
                __ATOMIC_RELAXED, __HIP_MEMORY_SCOPE_AGENT);
            uq[kk * 4 + j2] = val;
            bad |= (val == 0xFFFFFFFFFFFFFFFFull);
          }
        if (!__any(bad)) break;
        __builtin_amdgcn_s_sleep(1);
      }
      __builtin_amdgcn_sched_barrier(0);
    }

    // ---- re-arm slot (s+1)&3: sentinel own produce granule
    __hip_atomic_store(
        hx64 + ((size_t)(d * 4 + ((s + 1) & 3)) * BB + bcol) * 128 + (kg0 >> 1),
        0xFFFFFFFFFFFFFFFFull, __ATOMIC_RELAXED, __HIP_MEMORY_SCOPE_AGENT);

    // ---- MFMA over K=256: 6 independent chains (hi*bh | hi*bl | lo*bh)
    if (s == 0) {
      const float* hrow = h0 + ((size_t)d * BB + bcol) * HDIM;
#pragma unroll
      for (int kk = 0; kk < 8; ++kk) {
        float4 f0 = *(const float4*)(hrow + kk * 32 + l4 * 8);
        float4 f1 = *(const float4*)(hrow + kk * 32 + l4 * 8 + 4);
        float xf[8] = {f0.x, f0.y, f0.z, f0.w, f1.x, f1.y, f1.z, f1.w};
        bf16x8 bh, bl;
        pack_hilo(xf, bh, bl);
        accA = __builtin_amdgcn_mfma_f32_16x16x32_bf16(Ahi[0][kk], bh, accA, 0, 0, 0);
        accB = __builtin_amdgcn_mfma_f32_16x16x32_bf16(Ahi[0][kk], bl, accB, 0, 0, 0);
        accC = __builtin_amdgcn_mfma_f32_16x16x32_bf16(Alo[0][kk], bh, accC, 0, 0, 0);
        accD = __builtin_amdgcn_mfma_f32_16x16x32_bf16(Ahi[1][kk], bh, accD, 0, 0, 0);
        accE = __builtin_amdgcn_mfma_f32_16x16x32_bf16(Ahi[1][kk], bl, accE, 0, 0, 0);
        accF = __builtin_amdgcn_mfma_f32_16x16x32_bf16(Alo[1][kk], bh, accF, 0, 0, 0);
      }
    } else {
#pragma unroll
      for (int kk = 0; kk < 8; ++kk) {
        unsigned long long q0 = uq[kk * 4 + 0], q1 = uq[kk * 4 + 1];
        unsigned long long q2 = uq[kk * 4 + 2], q3 = uq[kk * 4 + 3];
        unsigned u[8] = {(unsigned)q0, (unsigned)(q0 >> 32),
                         (unsigned)q1, (unsigned)(q1 >> 32),
                         (unsigned)q2, (unsigned)(q2 >> 32),
                         (unsigned)q3, (unsigned)(q3 >> 32)};
        bf16x8 bh, bl;
        unpack8(u, bh, bl);
        accA = __builtin_amdgcn_mfma_f32_16x16x32_bf16(Ahi[0][kk], bh, accA, 0, 0, 0);
        accB = __builtin_amdgcn_mfma_f32_16x16x32_bf16(Ahi[0][kk], bl, accB, 0, 0, 0);
        accC = __builtin_amdgcn_mfma_f32_16x16x32_bf16(Alo[0][kk], bh, accC, 0, 0, 0);
        accD = __builtin_amdgcn_mfma_f32_16x16x32_bf16(Ahi[1][kk], bh, accD, 0, 0, 0);
        accE = __builtin_amdgcn_mfma_f32_16x16x32_bf16(Ahi[1][kk], bl, accE, 0, 0, 0);
        accF = __builtin_amdgcn_mfma_f32_16x16x32_bf16(Alo[1][kk], bh, accF, 0, 0, 0);
      }
    }
    f32x4 acc0 = accA + accB + accC;
    f32x4 acc1 = accD + accE + accF;

    // ---- cross-lane gate gather: partner lane = lane ^ 32 (l4 ^ 2)
    f32x4 r0, r1;
#pragma unroll
    for (int r = 0; r < 4; ++r) {
      r0[r] = __shfl_xor(acc0[r], 32);
      r1[r] = __shfl_xor(acc1[r], 32);
    }

    // ---- activations for units kg0, kg0+1 at col bcol (all in registers)
    float hn[2]; unsigned pv[2];
#pragma unroll
    for (int e = 0; e < 2; ++e) {
      float iv = low ? acc0[e]     : r0[2 + e];
      float fv = low ? r0[e]       : acc0[2 + e];
      float gv = low ? acc1[e]     : r1[2 + e];
      float ov = low ? r1[e]       : acc1[2 + e];
      float si = 1.f / (1.f + expf(-iv));
      float sf = 1.f / (1.f + expf(-fv));
      float so = 1.f / (1.f + expf(-ov));
      float cn = sf * c2[e] + si * tanhf(gv);
      c2[e] = cn;
      float h = so * tanhf(cn);
      hn[e] = h;
      unsigned short hb = bf16_rne(h);
      unsigned short lb = bf16_rne(h - bf16_tof(hb));
      pv[e] = (unsigned)hb | ((unsigned)lb << 16);
    }

    // drain re-arm (and poll loads) BEFORE produce becomes visible
    asm volatile("s_waitcnt vmcnt(0)" ::: "memory");

    unsigned long long pv64 =
        (unsigned long long)pv[0] | ((unsigned long long)pv[1] << 32);
    __hip_atomic_store(
        hx64 + ((size_t)(d * 4 + (s & 3)) * BB + bcol) * 128 + (kg0 >> 1),
        pv64, __ATOMIC_RELAXED, __HIP_MEMORY_SCOPE_AGENT);

    // hseq after produce: off the critical path
    hseq[(((size_t)d * SS + t) * HDIM + kg0) * BB + bcol] = hn[0];
    hseq[(((size_t)d * SS + t) * HDIM + kg0 + 1) * BB + bcol] = hn[1];
  }
}

// ---------------- K3: feats[t][b][tag] = [hf;hb] . Wt[tag] + bt -----------
__global__ void k3_feats(const float* __restrict__ hseq,
                         const float* __restrict__ Wt,
                         const float* __restrict__ bt,
                         float* __restrict__ feats) {
  int t = blockIdx.x, tid = threadIdx.x;
  __shared__ float Wl[NTAG][HID];
  for (int n = tid; n < NTAG * HID; n += 256) Wl[n >> 9][n & 511] = Wt[n];
  __syncthreads();
  int b = tid & 63, tq = tid >> 6;
  float acc[3];
  for (int c = 0; c < 3; ++c) acc[c] = bt[tq * 3 + c];
  const float* hf = hseq + ((size_t)0 * SS + t) * HDIM * BB;
  const float* hb = hseq + ((size_t)1 * SS + t) * HDIM * BB;
  for (int k = 0; k < HDIM; ++k) {
    float h1 = hf[(size_t)k * BB + b];
    float h2 = hb[(size_t)k * BB + b];
#pragma unroll
    for (int c = 0; c < 3; ++c) {
      acc[c] += h1 * Wl[tq * 3 + c][k];
      acc[c] += h2 * Wl[tq * 3 + c][HDIM + k];
    }
  }
  for (int c = 0; c < 3; ++c)
    feats[((size_t)t * BB + b) * NTAG + tq * 3 + c] = acc[c];
}

// ---------------- K4: Viterbi per batch element ---------------------------
__global__ void k4_viterbi(const float* __restrict__ feats,
                           const float* __restrict__ trans,
                           float* __restrict__ out) {
  int b = blockIdx.x, lane = threadIdx.x;   // 64 threads
  __shared__ float tr[NTAG][NTAG];
  __shared__ float fv[NTAG], fnew[NTAG], term[NTAG];
  __shared__ unsigned char bp[SS][NTAG];
  for (int n = lane; n < NTAG * NTAG; n += 64) tr[n / NTAG][n % NTAG] = trans[n];
  if (lane < NTAG) fv[lane] = (lane == START_TAG) ? 0.f : NEGV;
  __syncthreads();
  for (int s = 0; s < SS; ++s) {
    if (lane < NTAG) {
      float best = fv[0] + tr[lane][0]; int arg = 0;
#pragma unroll
      for (int j = 1; j < NTAG; ++j) {
        float vv = fv[j] + tr[lane][j];
        if (vv > best) { best = vv; arg = j; }
      }
      fnew[lane] = best + feats[((size_t)s * BB + b) * NTAG + lane];
      bp[s][lane] = (unsigned char)arg;
    }
    __syncthreads();
    if (lane < NTAG) fv[lane] = fnew[lane];
    __syncthreads();
  }
  if (lane < NTAG) {
    float vv = fv[lane] + tr[STOP_TAG][lane];
    if (lane == STOP_TAG || lane == START_TAG) vv = NEGV;
    term[lane] = vv;
  }
  __syncthreads();
  if (lane == 0) {
    float best = term[0]; int arg = 0;
    for (int j = 1; j < NTAG; ++j)
      if (term[j] > best) { best = term[j]; arg = j; }
    out[b] = best;
    int cur = arg;
    for (int s = SS - 1; s >= 0; --s) {
      out[64 + (size_t)b * SS + s] = (float)cur;
      cur = bp[s][cur];
    }
  }
}

// ---------------- launch ---------------------------------------------------
extern "C" void kernel_launch(void* const* d_in, const int* in_sizes, int n_in,
                              void* d_out, int out_size, void* d_ws, size_t ws_size,
                              hipStream_t stream) {
  (void)in_sizes; (void)n_in; (void)out_size;
  const int*   sent  = (const int*)d_in[0];
  const float* emb   = (const float*)d_in[4];
  const float* WihF  = (const float*)d_in[5];
  const float* WhhF  = (const float*)d_in[6];
  const float* bihF  = (const float*)d_in[7];
  const float* bhhF  = (const float*)d_in[8];
  const float* WihB  = (const float*)d_in[9];
  const float* WhhB  = (const float*)d_in[10];
  const float* bihB  = (const float*)d_in[11];
  const float* bhhB  = (const float*)d_in[12];
  const float* Wt    = (const float*)d_in[13];
  const float* bt    = (const float*)d_in[14];
  const float* trans = (const float*)d_in[15];
  const float* h0    = (const float*)d_in[16];
  const float* c0    = (const float*)d_in[17];
  float* out = (float*)d_out;

  char* ws = (char*)d_ws;
  // layout: hx ring 512KB | pre 134.2MB | region{ xpk 16MB (dead after k1)
  //         overlapped by hseq 33.5MB } | feats 768KB
  unsigned long long* hx64 = (unsigned long long*)ws;   // 2*4*64*256*4 = 512KB
  float* pre   = (float*)(ws + 524288ull);
  float* hseq  = (float*)(ws + 524288ull + 134217728ull);
  unsigned int* xpk = (unsigned int*)hseq;   // overlap: xpk dead before lstm
  float* feats = (float*)(ws + 524288ull + 134217728ull + 33554432ull);
  if (ws_size < 169082880ull) return;

  hipMemsetAsync(hx64, 0xFF, 524288ull, stream);   // arm all ring slots
  k0_gather<<<SS, 256, 0, stream>>>(sent, emb, xpk);
  k1_mfma<<<8192, 256, 0, stream>>>(xpk, WihF, WihB, bihF, bhhF, bihB, bhhB, pre);
  lstm_mfma<<<64, 256, 0, stream>>>(WhhF, WhhB, h0, c0, pre, hseq, hx64);
  k3_feats<<<SS, 256, 0, stream>>>(hseq, Wt, bt, feats);
  k4_viterbi<<<BB, 64, 0, stream>>>(feats, trans, out);
}

// Round 7
// 1619.623 us; speedup vs baseline: 1.5808x; 1.5808x over previous
//
#include <hip/hip_runtime.h>
#include <cstdint>
#include <cstddef>

#define EDIM 256
#define HID  512
#define NTAG 12
#define HDIM 256
#define BB   64
#define SS   256
#define START_TAG 10
#define STOP_TAG  11
#define NEGV (-10000.0f)
#define UPW  8           // h-units per WG (32 gate rows)

typedef __attribute__((ext_vector_type(8))) short bf16x8;
typedef __attribute__((ext_vector_type(4))) float f32x4;

__device__ __forceinline__ unsigned short bf16_rne(float x) {
  union { float f; unsigned u; } a; a.f = x;
  return (unsigned short)((a.u + 0x7fffu + ((a.u >> 16) & 1u)) >> 16);
}
__device__ __forceinline__ float bf16_tof(unsigned short h) {
  union { unsigned u; float f; } a; a.u = ((unsigned)h) << 16; return a.f;
}
__device__ __forceinline__ void unpack8(const unsigned* u, bf16x8& hi, bf16x8& lo) {
#pragma unroll
  for (int j = 0; j < 8; ++j) {
    hi[j] = (short)(u[j] & 0xffffu);
    lo[j] = (short)(u[j] >> 16);
  }
}
__device__ __forceinline__ void pack_hilo(const float* xf, bf16x8& hi, bf16x8& lo) {
#pragma unroll
  for (int j = 0; j < 8; ++j) {
    unsigned short hb = bf16_rne(xf[j]);
    hi[j] = (short)hb;
    lo[j] = (short)bf16_rne(xf[j] - bf16_tof(hb));
  }
}

// ---------------- K0: gather + split-bf16 pack  xpk[t][b][k] ---------------
__global__ void k0_gather(const int* __restrict__ sent,
                          const float* __restrict__ emb,
                          unsigned int* __restrict__ xpk) {
  int t = blockIdx.x;
  for (int n = threadIdx.x; n < BB * EDIM; n += 256) {
    int b = n >> 8, k = n & 255;
    int tok = sent[b * SS + t];
    float x = emb[(size_t)tok * EDIM + k];
    unsigned short hb = bf16_rne(x);
    unsigned short lb = bf16_rne(x - bf16_tof(hb));
    xpk[((size_t)t * BB + b) * EDIM + k] = (unsigned)hb | ((unsigned)lb << 16);
  }
}

// ---------------- K2: persistent fused BiLSTM ------------------------------
// 64 WGs: d = bid>>5, w = bid&31. WG owns h-units [w*8,w*8+8) (32 gate rows
// R = g*256 + w*8 + u). Wave v owns batch cols [v*16,v*16+16) end-to-end.
// Wih AND Whh split-bf16 fragments register-resident; x-projection MFMA runs
// BEFORE the poll (no h dependence -> hides in sync wait). Exchange: 4-slot
// ring hx[d][slot][k][b] (u32 granules; [k][b] => every 64B line is written
// by exactly ONE wave — single-writer lines, the round-6 lesson). Sentinel
// 0xFFFFFFFF (impossible for packed h, |h|<1). Producer order per step:
// poll -> re-arm slot(s+1) -> h-MFMA -> acts -> vmcnt(0) -> produce -> hseq.
__global__ void __launch_bounds__(256, 1)
lstm_fused(const float* __restrict__ WhhF, const float* __restrict__ WhhB,
           const float* __restrict__ WihF, const float* __restrict__ WihB,
           const float* __restrict__ bihF, const float* __restrict__ bhhF,
           const float* __restrict__ bihB, const float* __restrict__ bhhB,
           const unsigned int* __restrict__ xpk,
           const float* __restrict__ h0, const float* __restrict__ c0,
           float* __restrict__ hseq, unsigned int* __restrict__ hx) {
  const int bid = blockIdx.x;
  const int d = bid >> 5, w = bid & 31;
  const int tid = threadIdx.x;
  const int lane = tid & 63;
  const int v = tid >> 6;
  const int l15 = lane & 15, l4 = lane >> 4;
  const int bcol = v * 16 + l15;
  const int u2 = ((l4 & 1) << 2) | ((l4 >> 1) << 1);  // lane's unit-pair base
  const bool low = (l4 < 2);
  const int kg0 = w * UPW + u2;
  const float* Whh = d ? WhhB : WhhF;
  const float* Wih = d ? WihB : WihF;
  const float* bi  = d ? bihB : bihF;
  const float* bh  = d ? bhhB : bhhF;

  // ---- persistent A fragments (rows R(i) = (i>>3)*256 + w*8 + (i&7),
  //      i = rt*16 + l15; k = kk*32 + l4*8 + j)
  bf16x8 Hhi[2][8], Hlo[2][8], Xhi[2][8], Xlo[2][8];
#pragma unroll
  for (int rt = 0; rt < 2; ++rt) {
    int i = rt * 16 + l15;
    int R = ((i >> 3) << 8) + w * UPW + (i & 7);
    const float* wrow = Whh + (size_t)R * HDIM;
    const float* xrow = Wih + (size_t)R * EDIM;
#pragma unroll
    for (int kk = 0; kk < 8; ++kk) {
      {
        float4 f0 = *(const float4*)(wrow + kk * 32 + l4 * 8);
        float4 f1 = *(const float4*)(wrow + kk * 32 + l4 * 8 + 4);
        float xf[8] = {f0.x, f0.y, f0.z, f0.w, f1.x, f1.y, f1.z, f1.w};
        pack_hilo(xf, Hhi[rt][kk], Hlo[rt][kk]);
      }
      {
        float4 f0 = *(const float4*)(xrow + kk * 32 + l4 * 8);
        float4 f1 = *(const float4*)(xrow + kk * 32 + l4 * 8 + 4);
        float xf[8] = {f0.x, f0.y, f0.z, f0.w, f1.x, f1.y, f1.z, f1.w};
        pack_hilo(xf, Xhi[rt][kk], Xlo[rt][kk]);
      }
    }
  }
  // ---- per-lane bias for its 8 acc rows
  f32x4 bias0, bias1;
#pragma unroll
  for (int r = 0; r < 4; ++r) {
    int i0 = l4 * 4 + r;
    int R0 = ((i0 >> 3) << 8) + w * UPW + (i0 & 7);
    bias0[r] = bi[R0] + bh[R0];
    int i1 = 16 + i0;
    int R1 = ((i1 >> 3) << 8) + w * UPW + (i1 & 7);
    bias1[r] = bi[R1] + bh[R1];
  }
  // ---- register cell state: units kg0, kg0+1 at col bcol
  float c2[2];
  c2[0] = c0[((size_t)d * BB + bcol) * HDIM + kg0];
  c2[1] = c0[((size_t)d * BB + bcol) * HDIM + kg0 + 1];

  for (int s = 0; s < SS; ++s) {
    const int t = d ? (SS - 1 - s) : s;

    // ---- x fragments for step t (no h dependence)
    const unsigned int* xc = xpk + ((size_t)t * BB + bcol) * EDIM;
    uint4 xq[16];
#pragma unroll
    for (int kk = 0; kk < 8; ++kk) {
      xq[2 * kk]     = *(const uint4*)(xc + kk * 32 + l4 * 8);
      xq[2 * kk + 1] = *(const uint4*)(xc + kk * 32 + l4 * 8 + 4);
    }

    // ---- acc init + x-projection MFMA (runs before/under the poll wait)
    f32x4 accA = bias0, accD = bias1;
    f32x4 accB = {0.f, 0.f, 0.f, 0.f}, accC = accB, accE = accB, accF = accB;
#pragma unroll
    for (int kk = 0; kk < 8; ++kk) {
      unsigned u[8] = {xq[2 * kk].x, xq[2 * kk].y, xq[2 * kk].z, xq[2 * kk].w,
                       xq[2 * kk + 1].x, xq[2 * kk + 1].y,
                       xq[2 * kk + 1].z, xq[2 * kk + 1].w};
      bf16x8 xh, xl;
      unpack8(u, xh, xl);
      accA = __builtin_amdgcn_mfma_f32_16x16x32_bf16(Xhi[0][kk], xh, accA, 0, 0, 0);
      accB = __builtin_amdgcn_mfma_f32_16x16x32_bf16(Xhi[0][kk], xl, accB, 0, 0, 0);
      accC = __builtin_amdgcn_mfma_f32_16x16x32_bf16(Xlo[0][kk], xh, accC, 0, 0, 0);
      accD = __builtin_amdgcn_mfma_f32_16x16x32_bf16(Xhi[1][kk], xh, accD, 0, 0, 0);
      accE = __builtin_amdgcn_mfma_f32_16x16x32_bf16(Xhi[1][kk], xl, accE, 0, 0, 0);
      accF = __builtin_amdgcn_mfma_f32_16x16x32_bf16(Xlo[1][kk], xh, accF, 0, 0, 0);
    }

    // ---- data-poll: h_{s-1}, lane's 64 u32 granules ([k][b] layout)
    unsigned uv[64];
    if (s > 0) {
      const unsigned int* slot =
          hx + ((size_t)(d * 4 + ((s - 1) & 3)) * HDIM) * BB + bcol;
      while (true) {
        int bad = 0;
#pragma unroll
        for (int kk = 0; kk < 8; ++kk)
#pragma unroll
          for (int j = 0; j < 8; ++j) {
            unsigned val = __hip_atomic_load(
                slot + (size_t)(kk * 32 + l4 * 8 + j) * BB,
                __ATOMIC_RELAXED, __HIP_MEMORY_SCOPE_AGENT);
            uv[kk * 8 + j] = val;
            bad |= (val == 0xFFFFFFFFu);
          }
        if (!__any(bad)) break;
        __builtin_amdgcn_s_sleep(1);
      }
      __builtin_amdgcn_sched_barrier(0);
    }

    // ---- re-arm slot (s+1)&3: sentinel own 2 granules
    {
      unsigned int* ra =
          hx + ((size_t)(d * 4 + ((s + 1) & 3)) * HDIM) * BB + bcol;
      __hip_atomic_store(ra + (size_t)kg0 * BB, 0xFFFFFFFFu,
                         __ATOMIC_RELAXED, __HIP_MEMORY_SCOPE_AGENT);
      __hip_atomic_store(ra + (size_t)(kg0 + 1) * BB, 0xFFFFFFFFu,
                         __ATOMIC_RELAXED, __HIP_MEMORY_SCOPE_AGENT);
    }

    // ---- recurrent MFMA over K=256
    if (s == 0) {
      const float* hrow = h0 + ((size_t)d * BB + bcol) * HDIM;
#pragma unroll
      for (int kk = 0; kk < 8; ++kk) {
        float4 f0 = *(const float4*)(hrow + kk * 32 + l4 * 8);
        float4 f1 = *(const float4*)(hrow + kk * 32 + l4 * 8 + 4);
        float xf[8] = {f0.x, f0.y, f0.z, f0.w, f1.x, f1.y, f1.z, f1.w};
        bf16x8 bhf, blf;
        pack_hilo(xf, bhf, blf);
        accA = __builtin_amdgcn_mfma_f32_16x16x32_bf16(Hhi[0][kk], bhf, accA, 0, 0, 0);
        accB = __builtin_amdgcn_mfma_f32_16x16x32_bf16(Hhi[0][kk], blf, accB, 0, 0, 0);
        accC = __builtin_amdgcn_mfma_f32_16x16x32_bf16(Hlo[0][kk], bhf, accC, 0, 0, 0);
        accD = __builtin_amdgcn_mfma_f32_16x16x32_bf16(Hhi[1][kk], bhf, accD, 0, 0, 0);
        accE = __builtin_amdgcn_mfma_f32_16x16x32_bf16(Hhi[1][kk], blf, accE, 0, 0, 0);
        accF = __builtin_amdgcn_mfma_f32_16x16x32_bf16(Hlo[1][kk], bhf, accF, 0, 0, 0);
      }
    } else {
#pragma unroll
      for (int kk = 0; kk < 8; ++kk) {
        bf16x8 bhf, blf;
        unpack8(&uv[kk * 8], bhf, blf);
        accA = __builtin_amdgcn_mfma_f32_16x16x32_bf16(Hhi[0][kk], bhf, accA, 0, 0, 0);
        accB = __builtin_amdgcn_mfma_f32_16x16x32_bf16(Hhi[0][kk], blf, accB, 0, 0, 0);
        accC = __builtin_amdgcn_mfma_f32_16x16x32_bf16(Hlo[0][kk], bhf, accC, 0, 0, 0);
        accD = __builtin_amdgcn_mfma_f32_16x16x32_bf16(Hhi[1][kk], bhf, accD, 0, 0, 0);
        accE = __builtin_amdgcn_mfma_f32_16x16x32_bf16(Hhi[1][kk], blf, accE, 0, 0, 0);
        accF = __builtin_amdgcn_mfma_f32_16x16x32_bf16(Hlo[1][kk], bhf, accF, 0, 0, 0);
      }
    }
    f32x4 acc0 = accA + accB + accC;
    f32x4 acc1 = accD + accE + accF;

    // ---- cross-lane gate gather: partner lane = lane ^ 32 (l4 ^ 2)
    f32x4 r0, r1;
#pragma unroll
    for (int r = 0; r < 4; ++r) {
      r0[r] = __shfl_xor(acc0[r], 32);
      r1[r] = __shfl_xor(acc1[r], 32);
    }

    // ---- activations for units kg0, kg0+1 at col bcol (validated mapping)
    float hn[2]; unsigned pv[2];
#pragma unroll
    for (int e = 0; e < 2; ++e) {
      float iv = low ? acc0[e]     : r0[2 + e];
      float fv = low ? r0[e]       : acc0[2 + e];
      float gv = low ? acc1[e]     : r1[2 + e];
      float ov = low ? r1[e]       : acc1[2 + e];
      float si = 1.f / (1.f + expf(-iv));
      float sf = 1.f / (1.f + expf(-fv));
      float so = 1.f / (1.f + expf(-ov));
      float cn = sf * c2[e] + si * tanhf(gv);
      c2[e] = cn;
      float h = so * tanhf(cn);
      hn[e] = h;
      unsigned short hb2 = bf16_rne(h);
      unsigned short lb2 = bf16_rne(h - bf16_tof(hb2));
      pv[e] = (unsigned)hb2 | ((unsigned)lb2 << 16);
    }

    // drain re-arm + poll + x loads BEFORE produce becomes visible
    asm volatile("s_waitcnt vmcnt(0)" ::: "memory");

    {
      unsigned int* pd =
          hx + ((size_t)(d * 4 + (s & 3)) * HDIM) * BB + bcol;
      __hip_atomic_store(pd + (size_t)kg0 * BB, pv[0],
                         __ATOMIC_RELAXED, __HIP_MEMORY_SCOPE_AGENT);
      __hip_atomic_store(pd + (size_t)(kg0 + 1) * BB, pv[1],
                         __ATOMIC_RELAXED, __HIP_MEMORY_SCOPE_AGENT);
    }

    // hseq after produce: off the critical path
    hseq[(((size_t)d * SS + t) * HDIM + kg0) * BB + bcol] = hn[0];
    hseq[(((size_t)d * SS + t) * HDIM + kg0 + 1) * BB + bcol] = hn[1];
  }
}

// ---------------- K3: feats[t][b][tag] = [hf;hb] . Wt[tag] + bt -----------
__global__ void k3_feats(const float* __restrict__ hseq,
                         const float* __restrict__ Wt,
                         const float* __restrict__ bt,
                         float* __restrict__ feats) {
  int t = blockIdx.x, tid = threadIdx.x;
  __shared__ float Wl[NTAG][HID];
  for (int n = tid; n < NTAG * HID; n += 256) Wl[n >> 9][n & 511] = Wt[n];
  __syncthreads();
  int b = tid & 63, tq = tid >> 6;
  float acc[3];
  for (int c = 0; c < 3; ++c) acc[c] = bt[tq * 3 + c];
  const float* hf = hseq + ((size_t)0 * SS + t) * HDIM * BB;
  const float* hb = hseq + ((size_t)1 * SS + t) * HDIM * BB;
  for (int k = 0; k < HDIM; ++k) {
    float h1 = hf[(size_t)k * BB + b];
    float h2 = hb[(size_t)k * BB + b];
#pragma unroll
    for (int c = 0; c < 3; ++c) {
      acc[c] += h1 * Wl[tq * 3 + c][k];
      acc[c] += h2 * Wl[tq * 3 + c][HDIM + k];
    }
  }
  for (int c = 0; c < 3; ++c)
    feats[((size_t)t * BB + b) * NTAG + tq * 3 + c] = acc[c];
}

// ---------------- K4: Viterbi per batch element ---------------------------
__global__ void k4_viterbi(const float* __restrict__ feats,
                           const float* __restrict__ trans,
                           float* __restrict__ out) {
  int b = blockIdx.x, lane = threadIdx.x;   // 64 threads
  __shared__ float tr[NTAG][NTAG];
  __shared__ float fv[NTAG], fnew[NTAG], term[NTAG];
  __shared__ unsigned char bp[SS][NTAG];
  for (int n = lane; n < NTAG * NTAG; n += 64) tr[n / NTAG][n % NTAG] = trans[n];
  if (lane < NTAG) fv[lane] = (lane == START_TAG) ? 0.f : NEGV;
  __syncthreads();
  for (int s = 0; s < SS; ++s) {
    if (lane < NTAG) {
      float best = fv[0] + tr[lane][0]; int arg = 0;
#pragma unroll
      for (int j = 1; j < NTAG; ++j) {
        float vv = fv[j] + tr[lane][j];
        if (vv > best) { best = vv; arg = j; }
      }
      fnew[lane] = best + feats[((size_t)s * BB + b) * NTAG + lane];
      bp[s][lane] = (unsigned char)arg;
    }
    __syncthreads();
    if (lane < NTAG) fv[lane] = fnew[lane];
    __syncthreads();
  }
  if (lane < NTAG) {
    float vv = fv[lane] + tr[STOP_TAG][lane];
    if (lane == STOP_TAG || lane == START_TAG) vv = NEGV;
    term[lane] = vv;
  }
  __syncthreads();
  if (lane == 0) {
    float best = term[0]; int arg = 0;
    for (int j = 1; j < NTAG; ++j)
      if (term[j] > best) { best = term[j]; arg = j; }
    out[b] = best;
    int cur = arg;
    for (int s = SS - 1; s >= 0; --s) {
      out[64 + (size_t)b * SS + s] = (float)cur;
      cur = bp[s][cur];
    }
  }
}

// ---------------- launch ---------------------------------------------------
extern "C" void kernel_launch(void* const* d_in, const int* in_sizes, int n_in,
                              void* d_out, int out_size, void* d_ws, size_t ws_size,
                              hipStream_t stream) {
  (void)in_sizes; (void)n_in; (void)out_size;
  const int*   sent  = (const int*)d_in[0];
  const float* emb   = (const float*)d_in[4];
  const float* WihF  = (const float*)d_in[5];
  const float* WhhF  = (const float*)d_in[6];
  const float* bihF  = (const float*)d_in[7];
  const float* bhhF  = (const float*)d_in[8];
  const float* WihB  = (const float*)d_in[9];
  const float* WhhB  = (const float*)d_in[10];
  const float* bihB  = (const float*)d_in[11];
  const float* bhhB  = (const float*)d_in[12];
  const float* Wt    = (const float*)d_in[13];
  const float* bt    = (const float*)d_in[14];
  const float* trans = (const float*)d_in[15];
  const float* h0    = (const float*)d_in[16];
  const float* c0    = (const float*)d_in[17];
  float* out = (float*)d_out;

  char* ws = (char*)d_ws;
  // layout: hx ring 512KB | xpk 16MB | hseq 33.5MB | feats 768KB
  unsigned int* hx = (unsigned int*)ws;          // 2*4*256*64*4 = 512KB
  unsigned int* xpk = (unsigned int*)(ws + 524288ull);
  float* hseq  = (float*)(ws + 524288ull + 16777216ull);
  float* feats = (float*)(ws + 524288ull + 16777216ull + 33554432ull);
  if (ws_size < 52428800ull) return;

  hipMemsetAsync(hx, 0xFF, 524288ull, stream);   // arm all ring slots
  k0_gather<<<SS, 256, 0, stream>>>(sent, emb, xpk);
  lstm_fused<<<64, 256, 0, stream>>>(WhhF, WhhB, WihF, WihB,
                                     bihF, bhhF, bihB, bhhB,
                                     xpk, h0, c0, hseq, hx);
  k3_feats<<<SS, 256, 0, stream>>>(hseq, Wt, bt, feats);
  k4_viterbi<<<BB, 64, 0, stream>>>(feats, trans, out);
}

// Round 8
// 1593.219 us; speedup vs baseline: 1.6070x; 1.0166x over previous
//
#include <hip/hip_runtime.h>
#include <cstdint>
#include <cstddef>

#define EDIM 256
#define HID  512
#define NTAG 12
#define HDIM 256
#define BB   64
#define SS   256
#define START_TAG 10
#define STOP_TAG  11
#define NEGV (-10000.0f)
#define UPW  8           // h-units per WG (32 gate rows)

typedef __attribute__((ext_vector_type(8))) short bf16x8;
typedef __attribute__((ext_vector_type(4))) float f32x4;

__device__ __forceinline__ unsigned short bf16_rne(float x) {
  union { float f; unsigned u; } a; a.f = x;
  return (unsigned short)((a.u + 0x7fffu + ((a.u >> 16) & 1u)) >> 16);
}
__device__ __forceinline__ float bf16_tof(unsigned short h) {
  union { unsigned u; float f; } a; a.u = ((unsigned)h) << 16; return a.f;
}
__device__ __forceinline__ void unpack8(const unsigned* u, bf16x8& hi, bf16x8& lo) {
#pragma unroll
  for (int j = 0; j < 8; ++j) {
    hi[j] = (short)(u[j] & 0xffffu);
    lo[j] = (short)(u[j] >> 16);
  }
}
__device__ __forceinline__ void pack_hilo(const float* xf, bf16x8& hi, bf16x8& lo) {
#pragma unroll
  for (int j = 0; j < 8; ++j) {
    unsigned short hb = bf16_rne(xf[j]);
    hi[j] = (short)hb;
    lo[j] = (short)bf16_rne(xf[j] - bf16_tof(hb));
  }
}

// ---------------- K0: gather + split-bf16 pack  xpk[t][b][k] ---------------
__global__ void k0_gather(const int* __restrict__ sent,
                          const float* __restrict__ emb,
                          unsigned int* __restrict__ xpk) {
  int t = blockIdx.x;
  for (int n = threadIdx.x; n < BB * EDIM; n += 256) {
    int b = n >> 8, k = n & 255;
    int tok = sent[b * SS + t];
    float x = emb[(size_t)tok * EDIM + k];
    unsigned short hb = bf16_rne(x);
    unsigned short lb = bf16_rne(x - bf16_tof(hb));
    xpk[((size_t)t * BB + b) * EDIM + k] = (unsigned)hb | ((unsigned)lb << 16);
  }
}

// ---------------- K2: persistent fused BiLSTM, pipelined -------------------
// 64 WGs: d = bid>>5, w = bid&31. WG owns h-units [w*8,w*8+8). Wave v owns
// batch cols [v*16,v*16+16) end-to-end. Exchange ring (4 slots):
// hx[d][slot][group=k>>3][col][8 x u32]  -- one WG's 8 units per col = one
// 32B chunk; producer lane writes its 2 units as ONE u64 at natural offset
// p=u2>>1; consumer reads 2 x dwordx4 per kk (16 wide loads vs 64 scalar).
// 64B line = 2 cols x same group => single-writer wave. Sentinel 0xFFFFFFFF.
// Pipelining: x-projection MFMA for step s+1 runs AFTER produce(s) (in the
// sync slack); top of loop is poll-first.
// Producer order: poll -> re-arm(s+1) -> h-MFMA -> acts -> vmcnt(0) ->
// produce -> hseq -> x-load/x-MFMA(s+1).
__global__ void __launch_bounds__(256, 1)
lstm_fused(const float* __restrict__ WhhF, const float* __restrict__ WhhB,
           const float* __restrict__ WihF, const float* __restrict__ WihB,
           const float* __restrict__ bihF, const float* __restrict__ bhhF,
           const float* __restrict__ bihB, const float* __restrict__ bhhB,
           const unsigned int* __restrict__ xpk,
           const float* __restrict__ h0, const float* __restrict__ c0,
           float* __restrict__ hseq, unsigned int* __restrict__ hx) {
  const int bid = blockIdx.x;
  const int d = bid >> 5, w = bid & 31;
  const int tid = threadIdx.x;
  const int lane = tid & 63;
  const int v = tid >> 6;
  const int l15 = lane & 15, l4 = lane >> 4;
  const int bcol = v * 16 + l15;
  const int u2 = ((l4 & 1) << 2) | ((l4 >> 1) << 1);  // lane's unit-pair base
  const bool low = (l4 < 2);
  const int kg0 = w * UPW + u2;
  const float* Whh = d ? WhhB : WhhF;
  const float* Wih = d ? WihB : WihF;
  const float* bi  = d ? bihB : bihF;
  const float* bh  = d ? bhhB : bhhF;

  // ---- persistent A fragments (rows R(i) = (i>>3)*256 + w*8 + (i&7),
  //      i = rt*16 + l15; k = kk*32 + l4*8 + j)
  bf16x8 Hhi[2][8], Hlo[2][8], Xhi[2][8], Xlo[2][8];
#pragma unroll
  for (int rt = 0; rt < 2; ++rt) {
    int i = rt * 16 + l15;
    int R = ((i >> 3) << 8) + w * UPW + (i & 7);
    const float* wrow = Whh + (size_t)R * HDIM;
    const float* xrow = Wih + (size_t)R * EDIM;
#pragma unroll
    for (int kk = 0; kk < 8; ++kk) {
      {
        float4 f0 = *(const float4*)(wrow + kk * 32 + l4 * 8);
        float4 f1 = *(const float4*)(wrow + kk * 32 + l4 * 8 + 4);
        float xf[8] = {f0.x, f0.y, f0.z, f0.w, f1.x, f1.y, f1.z, f1.w};
        pack_hilo(xf, Hhi[rt][kk], Hlo[rt][kk]);
      }
      {
        float4 f0 = *(const float4*)(xrow + kk * 32 + l4 * 8);
        float4 f1 = *(const float4*)(xrow + kk * 32 + l4 * 8 + 4);
        float xf[8] = {f0.x, f0.y, f0.z, f0.w, f1.x, f1.y, f1.z, f1.w};
        pack_hilo(xf, Xhi[rt][kk], Xlo[rt][kk]);
      }
    }
  }
  // ---- per-lane bias for its 8 acc rows
  f32x4 bias0, bias1;
#pragma unroll
  for (int r = 0; r < 4; ++r) {
    int i0 = l4 * 4 + r;
    int R0 = ((i0 >> 3) << 8) + w * UPW + (i0 & 7);
    bias0[r] = bi[R0] + bh[R0];
    int i1 = 16 + i0;
    int R1 = ((i1 >> 3) << 8) + w * UPW + (i1 & 7);
    bias1[r] = bi[R1] + bh[R1];
  }
  // ---- register cell state: units kg0, kg0+1 at col bcol
  float c2[2];
  c2[0] = c0[((size_t)d * BB + bcol) * HDIM + kg0];
  c2[1] = c0[((size_t)d * BB + bcol) * HDIM + kg0 + 1];

  f32x4 accA, accB, accC, accD, accE, accF;

  // ---- x-projection for step 0 (preamble of the software pipeline)
  {
    const int t0 = d ? (SS - 1) : 0;
    const unsigned int* xc = xpk + ((size_t)t0 * BB + bcol) * EDIM;
    accA = bias0; accD = bias1;
    accB = (f32x4){0.f, 0.f, 0.f, 0.f}; accC = accB; accE = accB; accF = accB;
#pragma unroll
    for (int kk = 0; kk < 8; ++kk) {
      uint4 q0 = *(const uint4*)(xc + kk * 32 + l4 * 8);
      uint4 q1 = *(const uint4*)(xc + kk * 32 + l4 * 8 + 4);
      unsigned u[8] = {q0.x, q0.y, q0.z, q0.w, q1.x, q1.y, q1.z, q1.w};
      bf16x8 xh, xl;
      unpack8(u, xh, xl);
      accA = __builtin_amdgcn_mfma_f32_16x16x32_bf16(Xhi[0][kk], xh, accA, 0, 0, 0);
      accB = __builtin_amdgcn_mfma_f32_16x16x32_bf16(Xhi[0][kk], xl, accB, 0, 0, 0);
      accC = __builtin_amdgcn_mfma_f32_16x16x32_bf16(Xlo[0][kk], xh, accC, 0, 0, 0);
      accD = __builtin_amdgcn_mfma_f32_16x16x32_bf16(Xhi[1][kk], xh, accD, 0, 0, 0);
      accE = __builtin_amdgcn_mfma_f32_16x16x32_bf16(Xhi[1][kk], xl, accE, 0, 0, 0);
      accF = __builtin_amdgcn_mfma_f32_16x16x32_bf16(Xlo[1][kk], xh, accF, 0, 0, 0);
    }
  }

  // ring geometry (u32 units): slot = 32 groups * 64 cols * 8 = 16384 u32
  unsigned int* ringd = hx + (size_t)d * 4 * 16384;

  for (int s = 0; s < SS; ++s) {
    const int t = d ? (SS - 1 - s) : s;

    // ---- poll h_{s-1}: 16 x dwordx4 agent loads (sc1), sentinel check
    uint4 uq[16];
    if (s > 0) {
      const unsigned int* slotp = ringd + (size_t)((s - 1) & 3) * 16384;
      while (true) {
#pragma unroll
        for (int kk = 0; kk < 8; ++kk) {
          const unsigned int* p = slotp + ((kk * 4 + l4) * 64 + bcol) * 8;
          asm volatile("global_load_dwordx4 %0, %1, off sc1"
                       : "=v"(uq[2 * kk]) : "v"(p));
          asm volatile("global_load_dwordx4 %0, %1, off sc1"
                       : "=v"(uq[2 * kk + 1]) : "v"(p + 4));
        }
        asm volatile("s_waitcnt vmcnt(0)" ::: "memory");
        __builtin_amdgcn_sched_barrier(0);
        int bad = 0;
#pragma unroll
        for (int q = 0; q < 16; ++q) {
          bad |= (uq[q].x == 0xFFFFFFFFu) | (uq[q].y == 0xFFFFFFFFu) |
                 (uq[q].z == 0xFFFFFFFFu) | (uq[q].w == 0xFFFFFFFFu);
        }
        if (!__any(bad)) break;
        __builtin_amdgcn_s_sleep(1);
      }
      __builtin_amdgcn_sched_barrier(0);
    }

    // ---- re-arm slot (s+1)&3: sentinel own u64 granule
    {
      unsigned long long* ra = (unsigned long long*)(
          ringd + (size_t)((s + 1) & 3) * 16384) +
          ((size_t)w * 64 + bcol) * 4 + (u2 >> 1);
      __hip_atomic_store(ra, 0xFFFFFFFFFFFFFFFFull,
                         __ATOMIC_RELAXED, __HIP_MEMORY_SCOPE_AGENT);
    }

    // ---- recurrent MFMA over K=256 (accumulates into x-preacc)
    if (s == 0) {
      const float* hrow = h0 + ((size_t)d * BB + bcol) * HDIM;
#pragma unroll
      for (int kk = 0; kk < 8; ++kk) {
        float4 f0 = *(const float4*)(hrow + kk * 32 + l4 * 8);
        float4 f1 = *(const float4*)(hrow + kk * 32 + l4 * 8 + 4);
        float xf[8] = {f0.x, f0.y, f0.z, f0.w, f1.x, f1.y, f1.z, f1.w};
        bf16x8 bhf, blf;
        pack_hilo(xf, bhf, blf);
        accA = __builtin_amdgcn_mfma_f32_16x16x32_bf16(Hhi[0][kk], bhf, accA, 0, 0, 0);
        accB = __builtin_amdgcn_mfma_f32_16x16x32_bf16(Hhi[0][kk], blf, accB, 0, 0, 0);
        accC = __builtin_amdgcn_mfma_f32_16x16x32_bf16(Hlo[0][kk], bhf, accC, 0, 0, 0);
        accD = __builtin_amdgcn_mfma_f32_16x16x32_bf16(Hhi[1][kk], bhf, accD, 0, 0, 0);
        accE = __builtin_amdgcn_mfma_f32_16x16x32_bf16(Hhi[1][kk], blf, accE, 0, 0, 0);
        accF = __builtin_amdgcn_mfma_f32_16x16x32_bf16(Hlo[1][kk], bhf, accF, 0, 0, 0);
      }
    } else {
#pragma unroll
      for (int kk = 0; kk < 8; ++kk) {
        unsigned u[8] = {uq[2 * kk].x, uq[2 * kk].y, uq[2 * kk].z, uq[2 * kk].w,
                         uq[2 * kk + 1].x, uq[2 * kk + 1].y,
                         uq[2 * kk + 1].z, uq[2 * kk + 1].w};
        bf16x8 bhf, blf;
        unpack8(u, bhf, blf);
        accA = __builtin_amdgcn_mfma_f32_16x16x32_bf16(Hhi[0][kk], bhf, accA, 0, 0, 0);
        accB = __builtin_amdgcn_mfma_f32_16x16x32_bf16(Hhi[0][kk], blf, accB, 0, 0, 0);
        accC = __builtin_amdgcn_mfma_f32_16x16x32_bf16(Hlo[0][kk], bhf, accC, 0, 0, 0);
        accD = __builtin_amdgcn_mfma_f32_16x16x32_bf16(Hhi[1][kk], bhf, accD, 0, 0, 0);
        accE = __builtin_amdgcn_mfma_f32_16x16x32_bf16(Hhi[1][kk], blf, accE, 0, 0, 0);
        accF = __builtin_amdgcn_mfma_f32_16x16x32_bf16(Hlo[1][kk], bhf, accF, 0, 0, 0);
      }
    }
    f32x4 acc0 = accA + accB + accC;
    f32x4 acc1 = accD + accE + accF;

    // ---- cross-lane gate gather: partner lane = lane ^ 32 (l4 ^ 2)
    f32x4 r0, r1;
#pragma unroll
    for (int r = 0; r < 4; ++r) {
      r0[r] = __shfl_xor(acc0[r], 32);
      r1[r] = __shfl_xor(acc1[r], 32);
    }

    // ---- activations for units kg0, kg0+1 at col bcol
    float hn[2]; unsigned pv[2];
#pragma unroll
    for (int e = 0; e < 2; ++e) {
      float iv = low ? acc0[e]     : r0[2 + e];
      float fv = low ? r0[e]       : acc0[2 + e];
      float gv = low ? acc1[e]     : r1[2 + e];
      float ov = low ? r1[e]       : acc1[2 + e];
      float si = 1.f / (1.f + expf(-iv));
      float sf = 1.f / (1.f + expf(-fv));
      float so = 1.f / (1.f + expf(-ov));
      float cn = sf * c2[e] + si * tanhf(gv);
      c2[e] = cn;
      float h = so * tanhf(cn);
      hn[e] = h;
      unsigned short hb2 = bf16_rne(h);
      unsigned short lb2 = bf16_rne(h - bf16_tof(hb2));
      pv[e] = (unsigned)hb2 | ((unsigned)lb2 << 16);
    }

    // drain re-arm (+ everything outstanding) BEFORE produce becomes visible
    asm volatile("s_waitcnt vmcnt(0)" ::: "memory");

    {
      unsigned long long pv64 =
          (unsigned long long)pv[0] | ((unsigned long long)pv[1] << 32);
      unsigned long long* pd = (unsigned long long*)(
          ringd + (size_t)(s & 3) * 16384) +
          ((size_t)w * 64 + bcol) * 4 + (u2 >> 1);
      __hip_atomic_store(pd, pv64, __ATOMIC_RELAXED, __HIP_MEMORY_SCOPE_AGENT);
    }

    // ---- off-critical-path: hseq store + x-projection for step s+1
    hseq[(((size_t)d * SS + t) * HDIM + kg0) * BB + bcol] = hn[0];
    hseq[(((size_t)d * SS + t) * HDIM + kg0 + 1) * BB + bcol] = hn[1];

    if (s + 1 < SS) {
      const int tn = d ? (SS - 2 - s) : (s + 1);
      const unsigned int* xc = xpk + ((size_t)tn * BB + bcol) * EDIM;
      accA = bias0; accD = bias1;
      accB = (f32x4){0.f, 0.f, 0.f, 0.f}; accC = accB; accE = accB; accF = accB;
#pragma unroll
      for (int kk = 0; kk < 8; ++kk) {
        uint4 q0 = *(const uint4*)(xc + kk * 32 + l4 * 8);
        uint4 q1 = *(const uint4*)(xc + kk * 32 + l4 * 8 + 4);
        unsigned u[8] = {q0.x, q0.y, q0.z, q0.w, q1.x, q1.y, q1.z, q1.w};
        bf16x8 xh, xl;
        unpack8(u, xh, xl);
        accA = __builtin_amdgcn_mfma_f32_16x16x32_bf16(Xhi[0][kk], xh, accA, 0, 0, 0);
        accB = __builtin_amdgcn_mfma_f32_16x16x32_bf16(Xhi[0][kk], xl, accB, 0, 0, 0);
        accC = __builtin_amdgcn_mfma_f32_16x16x32_bf16(Xlo[0][kk], xh, accC, 0, 0, 0);
        accD = __builtin_amdgcn_mfma_f32_16x16x32_bf16(Xhi[1][kk], xh, accD, 0, 0, 0);
        accE = __builtin_amdgcn_mfma_f32_16x16x32_bf16(Xhi[1][kk], xl, accE, 0, 0, 0);
        accF = __builtin_amdgcn_mfma_f32_16x16x32_bf16(Xlo[1][kk], xh, accF, 0, 0, 0);
      }
    }
  }
}

// ---------------- K3: feats[t][b][tag] = [hf;hb] . Wt[tag] + bt -----------
__global__ void k3_feats(const float* __restrict__ hseq,
                         const float* __restrict__ Wt,
                         const float* __restrict__ bt,
                         float* __restrict__ feats) {
  int t = blockIdx.x, tid = threadIdx.x;
  __shared__ float Wl[NTAG][HID];
  for (int n = tid; n < NTAG * HID; n += 256) Wl[n >> 9][n & 511] = Wt[n];
  __syncthreads();
  int b = tid & 63, tq = tid >> 6;
  float acc[3];
  for (int c = 0; c < 3; ++c) acc[c] = bt[tq * 3 + c];
  const float* hf = hseq + ((size_t)0 * SS + t) * HDIM * BB;
  const float* hb = hseq + ((size_t)1 * SS + t) * HDIM * BB;
  for (int k = 0; k < HDIM; ++k) {
    float h1 = hf[(size_t)k * BB + b];
    float h2 = hb[(size_t)k * BB + b];
#pragma unroll
    for (int c = 0; c < 3; ++c) {
      acc[c] += h1 * Wl[tq * 3 + c][k];
      acc[c] += h2 * Wl[tq * 3 + c][HDIM + k];
    }
  }
  for (int c = 0; c < 3; ++c)
    feats[((size_t)t * BB + b) * NTAG + tq * 3 + c] = acc[c];
}

// ---------------- K4: Viterbi per batch element ---------------------------
__global__ void k4_viterbi(const float* __restrict__ feats,
                           const float* __restrict__ trans,
                           float* __restrict__ out) {
  int b = blockIdx.x, lane = threadIdx.x;   // 64 threads
  __shared__ float tr[NTAG][NTAG];
  __shared__ float fv[NTAG], fnew[NTAG], term[NTAG];
  __shared__ unsigned char bp[SS][NTAG];
  for (int n = lane; n < NTAG * NTAG; n += 64) tr[n / NTAG][n % NTAG] = trans[n];
  if (lane < NTAG) fv[lane] = (lane == START_TAG) ? 0.f : NEGV;
  __syncthreads();
  for (int s = 0; s < SS; ++s) {
    if (lane < NTAG) {
      float best = fv[0] + tr[lane][0]; int arg = 0;
#pragma unroll
      for (int j = 1; j < NTAG; ++j) {
        float vv = fv[j] + tr[lane][j];
        if (vv > best) { best = vv; arg = j; }
      }
      fnew[lane] = best + feats[((size_t)s * BB + b) * NTAG + lane];
      bp[s][lane] = (unsigned char)arg;
    }
    __syncthreads();
    if (lane < NTAG) fv[lane] = fnew[lane];
    __syncthreads();
  }
  if (lane < NTAG) {
    float vv = fv[lane] + tr[STOP_TAG][lane];
    if (lane == STOP_TAG || lane == START_TAG) vv = NEGV;
    term[lane] = vv;
  }
  __syncthreads();
  if (lane == 0) {
    float best = term[0]; int arg = 0;
    for (int j = 1; j < NTAG; ++j)
      if (term[j] > best) { best = term[j]; arg = j; }
    out[b] = best;
    int cur = arg;
    for (int s = SS - 1; s >= 0; --s) {
      out[64 + (size_t)b * SS + s] = (float)cur;
      cur = bp[s][cur];
    }
  }
}

// ---------------- launch ---------------------------------------------------
extern "C" void kernel_launch(void* const* d_in, const int* in_sizes, int n_in,
                              void* d_out, int out_size, void* d_ws, size_t ws_size,
                              hipStream_t stream) {
  (void)in_sizes; (void)n_in; (void)out_size;
  const int*   sent  = (const int*)d_in[0];
  const float* emb   = (const float*)d_in[4];
  const float* WihF  = (const float*)d_in[5];
  const float* WhhF  = (const float*)d_in[6];
  const float* bihF  = (const float*)d_in[7];
  const float* bhhF  = (const float*)d_in[8];
  const float* WihB  = (const float*)d_in[9];
  const float* WhhB  = (const float*)d_in[10];
  const float* bihB  = (const float*)d_in[11];
  const float* bhhB  = (const float*)d_in[12];
  const float* Wt    = (const float*)d_in[13];
  const float* bt    = (const float*)d_in[14];
  const float* trans = (const float*)d_in[15];
  const float* h0    = (const float*)d_in[16];
  const float* c0    = (const float*)d_in[17];
  float* out = (float*)d_out;

  char* ws = (char*)d_ws;
  // layout: hx ring 512KB | xpk 16MB | hseq 33.5MB | feats 768KB
  unsigned int* hx = (unsigned int*)ws;          // 2 dirs * 4 slots * 64KB
  unsigned int* xpk = (unsigned int*)(ws + 524288ull);
  float* hseq  = (float*)(ws + 524288ull + 16777216ull);
  float* feats = (float*)(ws + 524288ull + 16777216ull + 33554432ull);
  if (ws_size < 52428800ull) return;

  hipMemsetAsync(hx, 0xFF, 524288ull, stream);   // arm all ring slots
  k0_gather<<<SS, 256, 0, stream>>>(sent, emb, xpk);
  lstm_fused<<<64, 256, 0, stream>>>(WhhF, WhhB, WihF, WihB,
                                     bihF, bhhF, bihB, bhhB,
                                     xpk, h0, c0, hseq, hx);
  k3_feats<<<SS, 256, 0, stream>>>(hseq, Wt, bt, feats);
  k4_viterbi<<<BB, 64, 0, stream>>>(feats, trans, out);
}